// Round 1
// baseline (12147.543 us; speedup 1.0000x reference)
//
#include <hip/hip_runtime.h>
#include <hip/hip_bf16.h>
#include <math.h>

// DiffusionFlow: fused 10-step flow + log-det on MI355X.
// Streams: primal h (rows 0-31), tangent u0 (32-63), tangent u1 (64-95).
// Layers 1,2: M=96 x N=512 x K=512 bf16 MFMA GEMM per step.

typedef float f32x4 __attribute__((ext_vector_type(4)));
typedef __bf16 bf16x8 __attribute__((ext_vector_type(8)));

#define SWZ(row) (((row) & 7) << 4)

// ---- precompute: pack W (512x512 row-major fp32) into bf16 [k8][n][8] ----
// out[k8*4096 + n*8 + j] = bf16( W[n][k8*8 + j] )
__global__ void pack_w_kernel(const float* __restrict__ W,
                              __hip_bfloat16* __restrict__ out) {
    int i   = blockIdx.x * 512 + threadIdx.x;   // 0..262143
    int k8  = i >> 12;
    int rem = i & 4095;
    int n   = rem >> 3;
    int j   = rem & 7;
    out[i] = __float2bfloat16(W[n * 512 + (k8 << 3) + j]);
}

// ---- precompute: c_step[k][o] = b0[o] + W0[o,2:34] . temb(t_k) ----
__global__ void cstep_kernel(const float* __restrict__ W0,
                             const float* __restrict__ b0,
                             float* __restrict__ cst) {
    int k = blockIdx.x;     // 0..9
    int o = threadIdx.x;    // 0..511
    float t = (float)k * 0.1f;
    float acc = b0[o];
    #pragma unroll
    for (int j = 0; j < 16; ++j) {
        float f   = expf(-9.210340371976184f * (float)j / 16.0f);
        float arg = t * f;
        acc += W0[o * 34 + 2 + j]  * sinf(arg);
        acc += W0[o * 34 + 18 + j] * cosf(arg);
    }
    cst[k * 512 + o] = acc;
}

__global__ __launch_bounds__(512, 2)
void flow_kernel(const float* __restrict__ x,
                 const float* __restrict__ W0,
                 const float* __restrict__ cst,
                 const __hip_bfloat16* __restrict__ Wpk1,
                 const __hip_bfloat16* __restrict__ Wpk2,
                 const float* __restrict__ b1,
                 const float* __restrict__ b2,
                 const float* __restrict__ W3,
                 const float* __restrict__ b3v,
                 float* __restrict__ out)
{
    __shared__ __align__(16) __hip_bfloat16 Xbuf[96 * 512];  // 96 KB, XOR-swizzled rows
    __shared__ float zbuf[32][2];
    __shared__ float ldbuf[32];

    const int tid  = threadIdx.x;
    const int lane = tid & 63;
    const int wid  = tid >> 6;        // 0..7  -> N-slice n0 = wid*64
    const int l15  = lane & 15;
    const int lq   = lane >> 4;       // 0..3
    const int n0   = wid << 6;

    const int wgs = blockIdx.x << 5;  // 32 samples per WG

    if (tid < 32) {
        zbuf[tid][0] = x[(wgs + tid) * 2 + 0];
        zbuf[tid][1] = x[(wgs + tid) * 2 + 1];
        ldbuf[tid]   = 0.0f;
    }

    const int s3 = tid >> 4;          // sample 0..31 for L0/L3 mapping
    const int kb = (tid & 15) << 5;   // 32-col segment base for L0/L3

    // A-frag per-Mtile constants
    int arow[6], aswz[6];
    #pragma unroll
    for (int mt = 0; mt < 6; ++mt) {
        int row  = mt * 16 + l15;
        arow[mt] = row << 10;         // row * 1024 bytes
        aswz[mt] = SWZ(row);
    }
    const int  lq16 = lq << 4;
    const int  bidx = (lq << 9) + n0 + l15;   // uint4 index base into packed W
    const uint4* Wp1 = (const uint4*)Wpk1;
    const uint4* Wp2 = (const uint4*)Wpk2;

    __syncthreads();

    for (int step = 0; step < 10; ++step) {
        // ---------- layer 0 (rank-2 + step-constant) ----------
        {
            float z0 = zbuf[s3][0];
            float z1 = zbuf[s3][1];
            const float* cs = cst + step * 512;
            const int swz = SWZ(s3);              // same low-3 bits for s3, s3+32, s3+64
            char* base0 = (char*)Xbuf + (s3 << 10);
            #pragma unroll
            for (int m = 0; m < 4; ++m) {
                union { __hip_bfloat16 h[8]; uint4 u; } ph, p0, p1;
                #pragma unroll
                for (int j = 0; j < 8; ++j) {
                    int o = kb + m * 8 + j;
                    float w00 = W0[o * 34 + 0];
                    float w01 = W0[o * 34 + 1];
                    float a   = fmaf(z0, w00, fmaf(z1, w01, cs[o]));
                    float sig = 1.0f / (1.0f + __expf(-a));
                    float h   = a * sig;
                    float sp  = fmaf(h, 1.0f - sig, sig);   // silu'(a)
                    ph.h[j] = __float2bfloat16(h);
                    p0.h[j] = __float2bfloat16(sp * w00);
                    p1.h[j] = __float2bfloat16(sp * w01);
                }
                int off = ((kb + m * 8) * 2) ^ swz;
                *(uint4*)(base0 + off)               = ph.u;
                *(uint4*)(base0 + (32 << 10) + off)  = p0.u;
                *(uint4*)(base0 + (64 << 10) + off)  = p1.u;
            }
        }
        __syncthreads();

        // ---------- layers 1, 2: fused 96x512x512 MFMA GEMM ----------
        #pragma unroll
        for (int layer = 0; layer < 2; ++layer) {
            const uint4* Wp   = (layer == 0) ? Wp1 : Wp2;
            const float* bias = (layer == 0) ? b1  : b2;

            f32x4 acc[6][4];
            #pragma unroll
            for (int mt = 0; mt < 6; ++mt)
                #pragma unroll
                for (int nt = 0; nt < 4; ++nt)
                    acc[mt][nt] = (f32x4){0.f, 0.f, 0.f, 0.f};

            #pragma unroll 2
            for (int c = 0; c < 16; ++c) {        // K chunks of 32
                bf16x8 af[6], bfr[4];
                #pragma unroll
                for (int mt = 0; mt < 6; ++mt) {
                    int off = arow[mt] + (((c << 6) + lq16) ^ aswz[mt]);
                    uint4 v = *(const uint4*)((const char*)Xbuf + off);
                    af[mt] = __builtin_bit_cast(bf16x8, v);
                }
                const uint4* wc = Wp + (c << 11) + bidx;   // B-frags straight from L2
                #pragma unroll
                for (int nt = 0; nt < 4; ++nt)
                    bfr[nt] = __builtin_bit_cast(bf16x8, wc[nt << 4]);
                #pragma unroll
                for (int nt = 0; nt < 4; ++nt)
                    #pragma unroll
                    for (int mt = 0; mt < 6; ++mt)
                        acc[mt][nt] = __builtin_amdgcn_mfma_f32_16x16x32_bf16(
                            af[mt], bfr[nt], acc[mt][nt], 0, 0, 0);
            }

            float bv[4];
            #pragma unroll
            for (int nt = 0; nt < 4; ++nt)
                bv[nt] = bias[n0 + nt * 16 + l15];

            __syncthreads();   // all waves done reading Xbuf before overwrite

            // epilogue: silu + JVP coupling, all register-local per lane
            #pragma unroll
            for (int mt = 0; mt < 2; ++mt) {
                #pragma unroll
                for (int nt = 0; nt < 4; ++nt) {
                    #pragma unroll
                    for (int r = 0; r < 4; ++r) {
                        int row = mt * 16 + lq * 4 + r;       // C/D: row=(lane>>4)*4+reg
                        float a   = acc[mt][nt][r] + bv[nt];
                        float sig = 1.0f / (1.0f + __expf(-a));
                        float h   = a * sig;
                        float sp  = fmaf(h, 1.0f - sig, sig);
                        float u0  = sp * acc[mt + 2][nt][r];
                        float u1  = sp * acc[mt + 4][nt][r];
                        int off   = (((n0 + nt * 16 + l15) * 2) ^ SWZ(row));
                        char* p   = (char*)Xbuf + (row << 10) + off;
                        *(__hip_bfloat16*)p                = __float2bfloat16(h);
                        *(__hip_bfloat16*)(p + (32 << 10)) = __float2bfloat16(u0);
                        *(__hip_bfloat16*)(p + (64 << 10)) = __float2bfloat16(u1);
                    }
                }
            }
            __syncthreads();
        }

        // ---------- layer 3: six length-512 dots + state update ----------
        {
            float d0 = 0.f, d1 = 0.f, d2 = 0.f, d3 = 0.f, d4 = 0.f, d5 = 0.f;
            const float4* w3r0 = (const float4*)W3 + (kb >> 2);
            const float4* w3r1 = (const float4*)W3 + 128 + (kb >> 2);
            #pragma unroll
            for (int q = 0; q < 4; ++q) {
                float wa[8], wb[8];
                float4 v0 = w3r0[q * 2], v1 = w3r0[q * 2 + 1];
                wa[0]=v0.x; wa[1]=v0.y; wa[2]=v0.z; wa[3]=v0.w;
                wa[4]=v1.x; wa[5]=v1.y; wa[6]=v1.z; wa[7]=v1.w;
                float4 v2 = w3r1[q * 2], v3 = w3r1[q * 2 + 1];
                wb[0]=v2.x; wb[1]=v2.y; wb[2]=v2.z; wb[3]=v2.w;
                wb[4]=v3.x; wb[5]=v3.y; wb[6]=v3.z; wb[7]=v3.w;
                #pragma unroll
                for (int st = 0; st < 3; ++st) {
                    int row = s3 + st * 32;
                    int off = (row << 10) + (((kb * 2) + (q << 4)) ^ SWZ(row));
                    uint4 v = *(const uint4*)((const char*)Xbuf + off);
                    unsigned uu[4] = {v.x, v.y, v.z, v.w};
                    float e[8];
                    #pragma unroll
                    for (int w = 0; w < 4; ++w) {
                        e[2*w]   = __uint_as_float(uu[w] << 16);
                        e[2*w+1] = __uint_as_float(uu[w] & 0xffff0000u);
                    }
                    float sa = 0.f, sb = 0.f;
                    #pragma unroll
                    for (int j = 0; j < 8; ++j) {
                        sa = fmaf(wa[j], e[j], sa);
                        sb = fmaf(wb[j], e[j], sb);
                    }
                    if      (st == 0) { d0 += sa; d1 += sb; }
                    else if (st == 1) { d2 += sa; d3 += sb; }
                    else              { d4 += sa; d5 += sb; }
                }
            }
            #pragma unroll
            for (int m = 1; m < 16; m <<= 1) {
                d0 += __shfl_xor(d0, m);
                d1 += __shfl_xor(d1, m);
                d2 += __shfl_xor(d2, m);
                d3 += __shfl_xor(d3, m);
                d4 += __shfl_xor(d4, m);
                d5 += __shfl_xor(d5, m);
            }
            if ((tid & 15) == 0) {
                float v0 = d0 + b3v[0];
                float v1 = d1 + b3v[1];
                // col0 = dv/dz0 from u0: j00=d2, j10=d3 ; col1 from u1: j01=d4, j11=d5
                float det = (1.0f + 0.1f * d2) * (1.0f + 0.1f * d5)
                          - 0.01f * d4 * d3;
                ldbuf[s3] += logf(fmaxf(fabsf(det), 1e-8f));
                zbuf[s3][0] += 0.1f * v0;
                zbuf[s3][1] += 0.1f * v1;
            }
        }
        __syncthreads();
    }

    if (tid < 32) {
        float z0 = zbuf[tid][0], z1 = zbuf[tid][1];
        // log_pz = -0.5*(z0^2+z1^2) - log(2*pi)
        out[wgs + tid] = -0.5f * (z0 * z0 + z1 * z1) - 1.8378770664093453f + ldbuf[tid];
    }
}

extern "C" void kernel_launch(void* const* d_in, const int* in_sizes, int n_in,
                              void* d_out, int out_size, void* d_ws, size_t ws_size,
                              hipStream_t stream) {
    const float* x  = (const float*)d_in[0];
    const float* W0 = (const float*)d_in[1];   // (512, 34)
    const float* b0 = (const float*)d_in[2];
    const float* W1 = (const float*)d_in[3];   // (512, 512)
    const float* b1 = (const float*)d_in[4];
    const float* W2 = (const float*)d_in[5];
    const float* b2 = (const float*)d_in[6];
    const float* W3 = (const float*)d_in[7];   // (2, 512)
    const float* b3 = (const float*)d_in[8];
    float* out = (float*)d_out;

    char* ws = (char*)d_ws;
    __hip_bfloat16* wpk1 = (__hip_bfloat16*)ws;                 // 512 KB
    __hip_bfloat16* wpk2 = (__hip_bfloat16*)(ws + (512u << 10));// 512 KB
    float*          cstp = (float*)(ws + (1024u << 10));        // 20 KB

    pack_w_kernel<<<512, 512, 0, stream>>>(W1, wpk1);
    pack_w_kernel<<<512, 512, 0, stream>>>(W2, wpk2);
    cstep_kernel<<<10, 512, 0, stream>>>(W0, b0, cstp);
    flow_kernel<<<131072 / 32, 512, 0, stream>>>(x, W0, cstp, wpk1, wpk2,
                                                 b1, b2, W3, b3, out);
}

// Round 2
// 7152.791 us; speedup vs baseline: 1.6983x; 1.6983x over previous
//
#include <hip/hip_runtime.h>
#include <hip/hip_bf16.h>
#include <math.h>

// DiffusionFlow: fused 10-step flow + log-det on MI355X.
// Streams: primal h (Xbuf rows 0-31), tangent u0 (32-63), tangent u1 (64-95).
// Layers 1,2: D = W (A, global coalesced) @ X^T (B, LDS) per step.

typedef float f32x4 __attribute__((ext_vector_type(4)));
typedef __bf16 bf16x8 __attribute__((ext_vector_type(8)));

#define SWZ(row) (((row) & 7) << 4)

static __device__ __forceinline__ unsigned pkbf2(float a, float b) {
    unsigned short lo = __builtin_bit_cast(unsigned short, __float2bfloat16(a));
    unsigned short hi = __builtin_bit_cast(unsigned short, __float2bfloat16(b));
    return (unsigned)lo | ((unsigned)hi << 16);
}

// ---- pack W (512x512 row-major fp32) -> bf16 [c][n][32], c = k-chunk of 32 ----
// out[(c*512 + n)*32 + kk] = bf16( W[n][c*32 + kk] )
__global__ void pack_w_kernel(const float* __restrict__ W,
                              __hip_bfloat16* __restrict__ out) {
    int i  = blockIdx.x * 512 + threadIdx.x;   // 0..262143
    int c  = i >> 14;
    int n  = (i & 16383) >> 5;
    int kk = i & 31;
    out[i] = __float2bfloat16(W[n * 512 + (c << 5) + kk]);
}

// ---- pack W0 cols 0,1 -> contiguous [512][2] fp32 ----
__global__ void pack_w0_kernel(const float* __restrict__ W0,
                               float* __restrict__ w01) {
    int o = threadIdx.x;   // 512 threads, 1 block
    w01[o * 2 + 0] = W0[o * 34 + 0];
    w01[o * 2 + 1] = W0[o * 34 + 1];
}

// ---- c_step[k][o] = b0[o] + W0[o,2:34] . temb(t_k) ----
__global__ void cstep_kernel(const float* __restrict__ W0,
                             const float* __restrict__ b0,
                             float* __restrict__ cst) {
    int k = blockIdx.x;     // 0..9
    int o = threadIdx.x;    // 0..511
    float t = (float)k * 0.1f;
    float acc = b0[o];
    #pragma unroll
    for (int j = 0; j < 16; ++j) {
        float f   = expf(-9.210340371976184f * (float)j / 16.0f);
        float arg = t * f;
        acc += W0[o * 34 + 2 + j]  * sinf(arg);
        acc += W0[o * 34 + 18 + j] * cosf(arg);
    }
    cst[k * 512 + o] = acc;
}

__global__ __launch_bounds__(512)
__attribute__((amdgpu_waves_per_eu(2, 2)))
void flow_kernel(const float* __restrict__ x,
                 const float* __restrict__ w01,
                 const float* __restrict__ cst,
                 const __hip_bfloat16* __restrict__ Wpk1,
                 const __hip_bfloat16* __restrict__ Wpk2,
                 const float* __restrict__ b1,
                 const float* __restrict__ b2,
                 const float* __restrict__ W3,
                 const float* __restrict__ b3v,
                 float* __restrict__ out)
{
    __shared__ __align__(16) __hip_bfloat16 Xbuf[96 * 512];  // 96 KB, XOR-swizzled rows
    __shared__ float zbuf[32][2];
    __shared__ float ldbuf[32];

    const int tid  = threadIdx.x;
    const int lane = tid & 63;
    const int wid  = tid >> 6;        // 0..7  -> n-slice n0 = wid*64
    const int l15  = lane & 15;
    const int lq   = lane >> 4;       // 0..3
    const int n0   = wid << 6;
    const int wgs  = blockIdx.x << 5; // 32 samples per WG

    if (tid < 32) {
        zbuf[tid][0] = x[(wgs + tid) * 2 + 0];
        zbuf[tid][1] = x[(wgs + tid) * 2 + 1];
        ldbuf[tid]   = 0.0f;
    }

    const int s3 = tid >> 4;          // sample 0..31 for L0/L3 mapping
    const int kb = (tid & 15) << 5;   // 32-col segment base for L0/L3

    // B-frag (X from LDS) per-sample-tile constants
    int brow[6], bswz[6];
    #pragma unroll
    for (int mt = 0; mt < 6; ++mt) {
        int row  = mt * 16 + l15;
        brow[mt] = row << 10;         // row * 1024 bytes
        bswz[mt] = SWZ(row);
    }
    const int lq16  = lq << 4;
    const int abase = ((n0 + l15) << 2) + lq;   // uint4 index into packed W
    const uint4* Wp1 = (const uint4*)Wpk1;
    const uint4* Wp2 = (const uint4*)Wpk2;

    __syncthreads();

    #pragma unroll 1
    for (int step = 0; step < 10; ++step) {
        // ---------- layer 0 (rank-2 + step-constant) ----------
        {
            float z0 = zbuf[s3][0];
            float z1 = zbuf[s3][1];
            const float* cs = cst + (step << 9);
            const int swz = SWZ(s3);
            char* base0 = (char*)Xbuf + (s3 << 10);
            #pragma unroll
            for (int m = 0; m < 4; ++m) {
                unsigned ph[4], p0[4], p1[4];
                #pragma unroll
                for (int jj = 0; jj < 4; ++jj) {
                    float hv[2], u0v[2], u1v[2];
                    #pragma unroll
                    for (int k = 0; k < 2; ++k) {
                        int o = kb + m * 8 + jj * 2 + k;
                        float w00 = w01[o * 2 + 0];
                        float w01v = w01[o * 2 + 1];
                        float a   = fmaf(z0, w00, fmaf(z1, w01v, cs[o]));
                        float sig = 1.0f / (1.0f + __expf(-a));
                        float h   = a * sig;
                        float sp  = fmaf(h, 1.0f - sig, sig);   // silu'(a)
                        hv[k]  = h;
                        u0v[k] = sp * w00;
                        u1v[k] = sp * w01v;
                    }
                    ph[jj] = pkbf2(hv[0], hv[1]);
                    p0[jj] = pkbf2(u0v[0], u0v[1]);
                    p1[jj] = pkbf2(u1v[0], u1v[1]);
                }
                int off = ((kb + m * 8) * 2) ^ swz;
                uint4 vph = {ph[0], ph[1], ph[2], ph[3]};
                uint4 vp0 = {p0[0], p0[1], p0[2], p0[3]};
                uint4 vp1 = {p1[0], p1[1], p1[2], p1[3]};
                *(uint4*)(base0 + off)              = vph;
                *(uint4*)(base0 + (32 << 10) + off) = vp0;
                *(uint4*)(base0 + (64 << 10) + off) = vp1;
            }
        }
        __syncthreads();

        // ---------- layers 1, 2: D = W @ X^T, 512x96x512 ----------
        #pragma unroll 1
        for (int layer = 0; layer < 2; ++layer) {
            const uint4* __restrict__ Wp   = layer ? Wp2 : Wp1;
            const float* __restrict__ bias = layer ? b2  : b1;

            f32x4 acc[4][6];   // [n-tile][sample-tile]
            #pragma unroll
            for (int nt = 0; nt < 4; ++nt)
                #pragma unroll
                for (int mt = 0; mt < 6; ++mt)
                    acc[nt][mt] = (f32x4){0.f, 0.f, 0.f, 0.f};

            uint4  Af[4][4];   // W frags, 3-deep prefetch rotation
            bf16x8 Bf[2][6];   // X frags, 1-deep

            auto loada = [&](uint4 (&dst)[4], int c) {
                const uint4* p = Wp + c * 2048 + abase;
                dst[0] = p[0]; dst[1] = p[64]; dst[2] = p[128]; dst[3] = p[192];
            };
            auto loadb = [&](bf16x8 (&dst)[6], int c) {
                #pragma unroll
                for (int mt = 0; mt < 6; ++mt) {
                    int off = brow[mt] + (((c << 6) + lq16) ^ bswz[mt]);
                    dst[mt] = __builtin_bit_cast(bf16x8,
                        *(const uint4*)((const char*)Xbuf + off));
                }
            };

            loada(Af[0], 0); loada(Af[1], 1); loada(Af[2], 2);
            loadb(Bf[0], 0);

            #pragma unroll
            for (int c = 0; c < 16; ++c) {
                if (c + 3 < 16) loada(Af[(c + 3) & 3], c + 3);
                if (c + 1 < 16) loadb(Bf[(c + 1) & 1], c + 1);
                __builtin_amdgcn_s_setprio(1);
                #pragma unroll
                for (int nt = 0; nt < 4; ++nt)
                    #pragma unroll
                    for (int mt = 0; mt < 6; ++mt)
                        acc[nt][mt] = __builtin_amdgcn_mfma_f32_16x16x32_bf16(
                            __builtin_bit_cast(bf16x8, Af[c & 3][nt]),
                            Bf[c & 1][mt], acc[nt][mt], 0, 0, 0);
                __builtin_amdgcn_s_setprio(0);
            }

            f32x4 bv[4];
            #pragma unroll
            for (int nt = 0; nt < 4; ++nt)
                bv[nt] = *(const f32x4*)(bias + n0 + nt * 16 + (lq << 2));

            __syncthreads();   // all waves done reading Xbuf before overwrite

            // epilogue: silu + JVP coupling; writes are contiguous b64 per (mt,nt)
            #pragma unroll
            for (int mt = 0; mt < 2; ++mt) {
                int row = mt * 16 + l15;               // D col = sample
                char* pbase = (char*)Xbuf + (row << 10);
                int swz = SWZ(row);
                #pragma unroll
                for (int nt = 0; nt < 4; ++nt) {
                    unsigned hw[2], u0w[2], u1w[2];
                    #pragma unroll
                    for (int r2 = 0; r2 < 2; ++r2) {
                        float hv[2], u0v[2], u1v[2];
                        #pragma unroll
                        for (int k = 0; k < 2; ++k) {
                            int r = r2 * 2 + k;        // D row = n = n0+nt*16+lq*4+r
                            float a   = acc[nt][mt][r] + bv[nt][r];
                            float sig = 1.0f / (1.0f + __expf(-a));
                            float h   = a * sig;
                            float sp  = fmaf(h, 1.0f - sig, sig);
                            hv[k]  = h;
                            u0v[k] = sp * acc[nt][mt + 2][r];
                            u1v[k] = sp * acc[nt][mt + 4][r];
                        }
                        hw[r2]  = pkbf2(hv[0], hv[1]);
                        u0w[r2] = pkbf2(u0v[0], u0v[1]);
                        u1w[r2] = pkbf2(u1v[0], u1v[1]);
                    }
                    int off = (((n0 + nt * 16 + (lq << 2)) * 2) ^ swz);
                    uint2 vh = {hw[0], hw[1]};
                    uint2 v0 = {u0w[0], u0w[1]};
                    uint2 v1 = {u1w[0], u1w[1]};
                    *(uint2*)(pbase + off)              = vh;
                    *(uint2*)(pbase + (32 << 10) + off) = v0;
                    *(uint2*)(pbase + (64 << 10) + off) = v1;
                }
            }
            __syncthreads();
        }

        // ---------- layer 3: six length-512 dots + state update ----------
        {
            float d0 = 0.f, d1 = 0.f, d2 = 0.f, d3 = 0.f, d4 = 0.f, d5 = 0.f;
            const float4* w3r0 = (const float4*)W3 + (kb >> 2);
            const float4* w3r1 = (const float4*)W3 + 128 + (kb >> 2);
            #pragma unroll
            for (int q = 0; q < 4; ++q) {
                float wa[8], wb[8];
                float4 v0 = w3r0[q * 2], v1 = w3r0[q * 2 + 1];
                wa[0]=v0.x; wa[1]=v0.y; wa[2]=v0.z; wa[3]=v0.w;
                wa[4]=v1.x; wa[5]=v1.y; wa[6]=v1.z; wa[7]=v1.w;
                float4 v2 = w3r1[q * 2], v3 = w3r1[q * 2 + 1];
                wb[0]=v2.x; wb[1]=v2.y; wb[2]=v2.z; wb[3]=v2.w;
                wb[4]=v3.x; wb[5]=v3.y; wb[6]=v3.z; wb[7]=v3.w;
                #pragma unroll
                for (int st = 0; st < 3; ++st) {
                    int row = s3 + st * 32;
                    int off = (row << 10) + (((kb * 2) + (q << 4)) ^ SWZ(row));
                    uint4 v = *(const uint4*)((const char*)Xbuf + off);
                    unsigned uu[4] = {v.x, v.y, v.z, v.w};
                    float e[8];
                    #pragma unroll
                    for (int w = 0; w < 4; ++w) {
                        e[2*w]   = __uint_as_float(uu[w] << 16);
                        e[2*w+1] = __uint_as_float(uu[w] & 0xffff0000u);
                    }
                    float sa = 0.f, sb = 0.f;
                    #pragma unroll
                    for (int j = 0; j < 8; ++j) {
                        sa = fmaf(wa[j], e[j], sa);
                        sb = fmaf(wb[j], e[j], sb);
                    }
                    if      (st == 0) { d0 += sa; d1 += sb; }
                    else if (st == 1) { d2 += sa; d3 += sb; }
                    else              { d4 += sa; d5 += sb; }
                }
            }
            #pragma unroll
            for (int m = 1; m < 16; m <<= 1) {
                d0 += __shfl_xor(d0, m);
                d1 += __shfl_xor(d1, m);
                d2 += __shfl_xor(d2, m);
                d3 += __shfl_xor(d3, m);
                d4 += __shfl_xor(d4, m);
                d5 += __shfl_xor(d5, m);
            }
            if ((tid & 15) == 0) {
                float v0 = d0 + b3v[0];
                float v1 = d1 + b3v[1];
                float det = (1.0f + 0.1f * d2) * (1.0f + 0.1f * d5)
                          - 0.01f * d4 * d3;
                ldbuf[s3] += logf(fmaxf(fabsf(det), 1e-8f));
                zbuf[s3][0] += 0.1f * v0;
                zbuf[s3][1] += 0.1f * v1;
            }
        }
        __syncthreads();
    }

    if (tid < 32) {
        float z0 = zbuf[tid][0], z1 = zbuf[tid][1];
        out[wgs + tid] = -0.5f * (z0 * z0 + z1 * z1) - 1.8378770664093453f + ldbuf[tid];
    }
}

extern "C" void kernel_launch(void* const* d_in, const int* in_sizes, int n_in,
                              void* d_out, int out_size, void* d_ws, size_t ws_size,
                              hipStream_t stream) {
    const float* x  = (const float*)d_in[0];
    const float* W0 = (const float*)d_in[1];   // (512, 34)
    const float* b0 = (const float*)d_in[2];
    const float* W1 = (const float*)d_in[3];   // (512, 512)
    const float* b1 = (const float*)d_in[4];
    const float* W2 = (const float*)d_in[5];
    const float* b2 = (const float*)d_in[6];
    const float* W3 = (const float*)d_in[7];   // (2, 512)
    const float* b3 = (const float*)d_in[8];
    float* out = (float*)d_out;

    char* ws = (char*)d_ws;
    __hip_bfloat16* wpk1 = (__hip_bfloat16*)ws;                  // 512 KB
    __hip_bfloat16* wpk2 = (__hip_bfloat16*)(ws + (512u << 10)); // 512 KB
    float*          cstp = (float*)(ws + (1024u << 10));         // 20 KB
    float*          w01p = (float*)(ws + (1044u << 10));         // 4 KB

    pack_w_kernel<<<512, 512, 0, stream>>>(W1, wpk1);
    pack_w_kernel<<<512, 512, 0, stream>>>(W2, wpk2);
    cstep_kernel<<<10, 512, 0, stream>>>(W0, b0, cstp);
    pack_w0_kernel<<<1, 512, 0, stream>>>(W0, w01p);
    flow_kernel<<<131072 / 32, 512, 0, stream>>>(x, w01p, cstp, wpk1, wpk2,
                                                 b1, b2, W3, b3, out);
}

// Round 3
// 6818.114 us; speedup vs baseline: 1.7817x; 1.0491x over previous
//
#include <hip/hip_runtime.h>
#include <hip/hip_bf16.h>
#include <math.h>

// DiffusionFlow: fused 10-step flow + log-det on MI355X.
// Streams in Xbuf: primal h rows 0-31, tangent u0 rows 32-63, tangent u1 rows 64-95.
// Layers 1,2: D = W (A, global/L2 coalesced) @ X^T (B, LDS), 512x96x512.
// 1024 threads = 16 waves; wave w owns output cols [w*32, w*32+32) x all 96 rows.
// acc[2][6]=48 regs, A-frags depth-2x2=16, B-frags 1x6=24 -> fits 128-reg budget
// (16 resident waves mandate <=128 VGPRs; round-2's 208-reg live set spilled 1.9GB).

typedef float f32x4 __attribute__((ext_vector_type(4)));
typedef __bf16 bf16x8 __attribute__((ext_vector_type(8)));

#define SWZ(row) (((row) & 7) << 4)

static __device__ __forceinline__ unsigned pkbf2(float a, float b) {
    unsigned short lo = __builtin_bit_cast(unsigned short, __float2bfloat16(a));
    unsigned short hi = __builtin_bit_cast(unsigned short, __float2bfloat16(b));
    return (unsigned)lo | ((unsigned)hi << 16);
}

// ---- pack W (512x512 row-major fp32) -> bf16 [c][n][32], c = k-chunk of 32 ----
__global__ void pack_w_kernel(const float* __restrict__ W,
                              __hip_bfloat16* __restrict__ out) {
    int i  = blockIdx.x * 512 + threadIdx.x;
    int c  = i >> 14;
    int n  = (i & 16383) >> 5;
    int kk = i & 31;
    out[i] = __float2bfloat16(W[n * 512 + (c << 5) + kk]);
}

// ---- pack W0 cols 0,1 -> contiguous [512][2] fp32 ----
__global__ void pack_w0_kernel(const float* __restrict__ W0,
                               float* __restrict__ w01) {
    int o = threadIdx.x;
    w01[o * 2 + 0] = W0[o * 34 + 0];
    w01[o * 2 + 1] = W0[o * 34 + 1];
}

// ---- c_step[k][o] = b0[o] + W0[o,2:34] . temb(t_k) ----
__global__ void cstep_kernel(const float* __restrict__ W0,
                             const float* __restrict__ b0,
                             float* __restrict__ cst) {
    int k = blockIdx.x;
    int o = threadIdx.x;
    float t = (float)k * 0.1f;
    float acc = b0[o];
    #pragma unroll
    for (int j = 0; j < 16; ++j) {
        float f   = expf(-9.210340371976184f * (float)j / 16.0f);
        float arg = t * f;
        acc += W0[o * 34 + 2 + j]  * sinf(arg);
        acc += W0[o * 34 + 18 + j] * cosf(arg);
    }
    cst[k * 512 + o] = acc;
}

__global__ __launch_bounds__(1024)
__attribute__((amdgpu_waves_per_eu(4)))
void flow_kernel(const float* __restrict__ x,
                 const float* __restrict__ w01,
                 const float* __restrict__ cst,
                 const __hip_bfloat16* __restrict__ Wpk1,
                 const __hip_bfloat16* __restrict__ Wpk2,
                 const float* __restrict__ b1,
                 const float* __restrict__ b2,
                 const float* __restrict__ W3,
                 const float* __restrict__ b3v,
                 float* __restrict__ out)
{
    __shared__ __align__(16) __hip_bfloat16 Xbuf[96 * 512];  // 96 KB, XOR-swizzled rows
    __shared__ float zbuf[32][2];
    __shared__ float ldbuf[32];

    const int tid  = threadIdx.x;
    const int lane = tid & 63;
    const int wid  = tid >> 6;        // 0..15 -> n-slice n0w = wid*32
    const int l15  = lane & 15;
    const int lq   = lane >> 4;       // 0..3
    const int n0w  = wid << 5;
    const int wgs  = blockIdx.x << 5; // 32 samples per WG

    if (tid < 32) {
        zbuf[tid][0] = x[(wgs + tid) * 2 + 0];
        zbuf[tid][1] = x[(wgs + tid) * 2 + 1];
        ldbuf[tid]   = 0.0f;
    }

    // B-frag (X from LDS) per-sample-tile constants
    int brow[6], bswz[6];
    #pragma unroll
    for (int mt = 0; mt < 6; ++mt) {
        int row  = mt * 16 + l15;
        brow[mt] = row << 10;         // row * 1024 bytes
        bswz[mt] = SWZ(row);
    }
    const int lq16  = lq << 4;
    const int abase = ((n0w + l15) << 2) + lq;   // uint4 index into packed W
    const uint4* Wp1 = (const uint4*)Wpk1;
    const uint4* Wp2 = (const uint4*)Wpk2;

    __syncthreads();

    #pragma unroll 1
    for (int step = 0; step < 10; ++step) {
        // ---------- layer 0 (rank-2 + step-constant): 16 outputs/thread ----------
        {
            const int s0 = tid >> 5;          // sample 0..31
            const int ob = (tid & 31) << 4;   // element base, 16 outs
            float z0 = zbuf[s0][0];
            float z1 = zbuf[s0][1];
            const float* cs = cst + (step << 9);
            const int swz = SWZ(s0);
            char* base0 = (char*)Xbuf + (s0 << 10);
            #pragma unroll
            for (int m = 0; m < 2; ++m) {
                unsigned ph[4], p0[4], p1[4];
                #pragma unroll
                for (int jj = 0; jj < 4; ++jj) {
                    float hv[2], u0v[2], u1v[2];
                    #pragma unroll
                    for (int k = 0; k < 2; ++k) {
                        int o = ob + m * 8 + jj * 2 + k;
                        float w00  = w01[o * 2 + 0];
                        float w01v = w01[o * 2 + 1];
                        float a   = fmaf(z0, w00, fmaf(z1, w01v, cs[o]));
                        float sig = 1.0f / (1.0f + __expf(-a));
                        float h   = a * sig;
                        float sp  = fmaf(h, 1.0f - sig, sig);   // silu'(a)
                        hv[k]  = h;
                        u0v[k] = sp * w00;
                        u1v[k] = sp * w01v;
                    }
                    ph[jj] = pkbf2(hv[0], hv[1]);
                    p0[jj] = pkbf2(u0v[0], u0v[1]);
                    p1[jj] = pkbf2(u1v[0], u1v[1]);
                }
                int off = ((ob + m * 8) * 2) ^ swz;
                uint4 vph = {ph[0], ph[1], ph[2], ph[3]};
                uint4 vp0 = {p0[0], p0[1], p0[2], p0[3]};
                uint4 vp1 = {p1[0], p1[1], p1[2], p1[3]};
                *(uint4*)(base0 + off)              = vph;
                *(uint4*)(base0 + (32 << 10) + off) = vp0;
                *(uint4*)(base0 + (64 << 10) + off) = vp1;
            }
        }
        __syncthreads();

        // ---------- layers 1, 2: D = W @ X^T, 512x96x512 ----------
        #pragma unroll 1
        for (int layer = 0; layer < 2; ++layer) {
            const uint4* __restrict__ Wp   = layer ? Wp2 : Wp1;
            const float* __restrict__ bias = layer ? b2  : b1;

            f32x4 acc[2][6];   // [n-tile][sample-tile]
            #pragma unroll
            for (int nt = 0; nt < 2; ++nt)
                #pragma unroll
                for (int mt = 0; mt < 6; ++mt)
                    acc[nt][mt] = (f32x4){0.f, 0.f, 0.f, 0.f};

            uint4  Af[2][2];   // W frags, depth-2 rotation
            bf16x8 Bf[6];      // X frags, single-buffered

            auto loada = [&](uint4 (&dst)[2], int c) {
                const uint4* p = Wp + c * 2048 + abase;
                dst[0] = p[0]; dst[1] = p[64];
            };

            loada(Af[0], 0);

            #pragma unroll
            for (int c = 0; c < 16; ++c) {
                if (c + 1 < 16) loada(Af[(c + 1) & 1], c + 1);
                #pragma unroll
                for (int mt = 0; mt < 6; ++mt) {
                    int off = brow[mt] + (((c << 6) + lq16) ^ bswz[mt]);
                    Bf[mt] = __builtin_bit_cast(bf16x8,
                        *(const uint4*)((const char*)Xbuf + off));
                }
                __builtin_amdgcn_s_setprio(1);
                #pragma unroll
                for (int mt = 0; mt < 6; ++mt)
                    #pragma unroll
                    for (int nt = 0; nt < 2; ++nt)
                        acc[nt][mt] = __builtin_amdgcn_mfma_f32_16x16x32_bf16(
                            __builtin_bit_cast(bf16x8, Af[c & 1][nt]),
                            Bf[mt], acc[nt][mt], 0, 0, 0);
                __builtin_amdgcn_s_setprio(0);
            }

            f32x4 bv[2];
            #pragma unroll
            for (int nt = 0; nt < 2; ++nt)
                bv[nt] = *(const f32x4*)(bias + n0w + nt * 16 + (lq << 2));

            __syncthreads();   // all waves done reading Xbuf before overwrite

            // epilogue: silu + JVP coupling; 12 uint2 LDS writes/thread
            #pragma unroll
            for (int mt = 0; mt < 2; ++mt) {
                int row = mt * 16 + l15;               // D col = sample
                char* pbase = (char*)Xbuf + (row << 10);
                int swz = SWZ(row);
                #pragma unroll
                for (int nt = 0; nt < 2; ++nt) {
                    unsigned hw[2], u0w[2], u1w[2];
                    #pragma unroll
                    for (int r2 = 0; r2 < 2; ++r2) {
                        float hv[2], u0v[2], u1v[2];
                        #pragma unroll
                        for (int k = 0; k < 2; ++k) {
                            int r = r2 * 2 + k;        // D row = n = n0w+nt*16+lq*4+r
                            float a   = acc[nt][mt][r] + bv[nt][r];
                            float sig = 1.0f / (1.0f + __expf(-a));
                            float h   = a * sig;
                            float sp  = fmaf(h, 1.0f - sig, sig);
                            hv[k]  = h;
                            u0v[k] = sp * acc[nt][mt + 2][r];
                            u1v[k] = sp * acc[nt][mt + 4][r];
                        }
                        hw[r2]  = pkbf2(hv[0], hv[1]);
                        u0w[r2] = pkbf2(u0v[0], u0v[1]);
                        u1w[r2] = pkbf2(u1v[0], u1v[1]);
                    }
                    int off = (((n0w + nt * 16 + (lq << 2)) * 2) ^ swz);
                    uint2 vh = {hw[0], hw[1]};
                    uint2 v0 = {u0w[0], u0w[1]};
                    uint2 v1 = {u1w[0], u1w[1]};
                    *(uint2*)(pbase + off)              = vh;
                    *(uint2*)(pbase + (32 << 10) + off) = v0;
                    *(uint2*)(pbase + (64 << 10) + off) = v1;
                }
            }
            __syncthreads();
        }

        // ---------- layer 3: six length-512 dots + state update ----------
        {
            const int s0   = tid >> 5;         // sample
            const int cidx = tid & 31;         // col-chunk: 16 elems
            float d0 = 0.f, d1 = 0.f, d2 = 0.f, d3 = 0.f, d4 = 0.f, d5 = 0.f;
            float wa[16], wb[16];
            const float4* w3r0 = (const float4*)W3 + (cidx << 2);
            const float4* w3r1 = (const float4*)W3 + 128 + (cidx << 2);
            #pragma unroll
            for (int q = 0; q < 4; ++q) {
                float4 v0 = w3r0[q], v1 = w3r1[q];
                wa[4*q+0]=v0.x; wa[4*q+1]=v0.y; wa[4*q+2]=v0.z; wa[4*q+3]=v0.w;
                wb[4*q+0]=v1.x; wb[4*q+1]=v1.y; wb[4*q+2]=v1.z; wb[4*q+3]=v1.w;
            }
            #pragma unroll
            for (int st = 0; st < 3; ++st) {
                int row = s0 + st * 32;
                const char* rb = (const char*)Xbuf + (row << 10);
                int swz = SWZ(row);
                float e[16];
                #pragma unroll
                for (int q = 0; q < 2; ++q) {
                    int off = (((cidx << 5) + (q << 4)) ^ swz);
                    uint4 v = *(const uint4*)(rb + off);
                    unsigned uu[4] = {v.x, v.y, v.z, v.w};
                    #pragma unroll
                    for (int w = 0; w < 4; ++w) {
                        e[q*8 + 2*w]   = __uint_as_float(uu[w] << 16);
                        e[q*8 + 2*w+1] = __uint_as_float(uu[w] & 0xffff0000u);
                    }
                }
                float sa = 0.f, sb = 0.f;
                #pragma unroll
                for (int j = 0; j < 16; ++j) {
                    sa = fmaf(wa[j], e[j], sa);
                    sb = fmaf(wb[j], e[j], sb);
                }
                if      (st == 0) { d0 = sa; d1 = sb; }
                else if (st == 1) { d2 = sa; d3 = sb; }
                else              { d4 = sa; d5 = sb; }
            }
            #pragma unroll
            for (int m = 1; m < 32; m <<= 1) {
                d0 += __shfl_xor(d0, m);
                d1 += __shfl_xor(d1, m);
                d2 += __shfl_xor(d2, m);
                d3 += __shfl_xor(d3, m);
                d4 += __shfl_xor(d4, m);
                d5 += __shfl_xor(d5, m);
            }
            if ((tid & 31) == 0) {
                float v0 = d0 + b3v[0];
                float v1 = d1 + b3v[1];
                float det = (1.0f + 0.1f * d2) * (1.0f + 0.1f * d5)
                          - 0.01f * d4 * d3;
                ldbuf[s0] += logf(fmaxf(fabsf(det), 1e-8f));
                zbuf[s0][0] += 0.1f * v0;
                zbuf[s0][1] += 0.1f * v1;
            }
        }
        __syncthreads();
    }

    if (tid < 32) {
        float z0 = zbuf[tid][0], z1 = zbuf[tid][1];
        out[wgs + tid] = -0.5f * (z0 * z0 + z1 * z1) - 1.8378770664093453f + ldbuf[tid];
    }
}

extern "C" void kernel_launch(void* const* d_in, const int* in_sizes, int n_in,
                              void* d_out, int out_size, void* d_ws, size_t ws_size,
                              hipStream_t stream) {
    const float* x  = (const float*)d_in[0];
    const float* W0 = (const float*)d_in[1];   // (512, 34)
    const float* b0 = (const float*)d_in[2];
    const float* W1 = (const float*)d_in[3];   // (512, 512)
    const float* b1 = (const float*)d_in[4];
    const float* W2 = (const float*)d_in[5];
    const float* b2 = (const float*)d_in[6];
    const float* W3 = (const float*)d_in[7];   // (2, 512)
    const float* b3 = (const float*)d_in[8];
    float* out = (float*)d_out;

    char* ws = (char*)d_ws;
    __hip_bfloat16* wpk1 = (__hip_bfloat16*)ws;                  // 512 KB
    __hip_bfloat16* wpk2 = (__hip_bfloat16*)(ws + (512u << 10)); // 512 KB
    float*          cstp = (float*)(ws + (1024u << 10));         // 20 KB
    float*          w01p = (float*)(ws + (1044u << 10));         // 4 KB

    pack_w_kernel<<<512, 512, 0, stream>>>(W1, wpk1);
    pack_w_kernel<<<512, 512, 0, stream>>>(W2, wpk2);
    cstep_kernel<<<10, 512, 0, stream>>>(W0, b0, cstp);
    pack_w0_kernel<<<1, 512, 0, stream>>>(W0, w01p);
    flow_kernel<<<131072 / 32, 1024, 0, stream>>>(x, w01p, cstp, wpk1, wpk2,
                                                  b1, b2, W3, b3, out);
}

// Round 4
// 6549.474 us; speedup vs baseline: 1.8547x; 1.0410x over previous
//
#include <hip/hip_runtime.h>
#include <hip/hip_bf16.h>
#include <math.h>

// DiffusionFlow: fused 10-step flow + log-det on MI355X.
// Streams in Xbuf: primal h rows 0-31, tangent u0 rows 32-63, tangent u1 rows 64-95.
// Layers 1,2: D = W (A, global/L2 coalesced) @ X^T (B, LDS), 512x96x512.
// 1024 threads = 16 waves; wave w owns output cols [w*32, w*32+32) x all 96 rows.
// waves_per_eu(4,4): LDS (96KB) caps at 1 WG/CU = 16 waves = 4 waves/EU, so the
// correct VGPR budget is 128. Round 3's waves_per_eu(4) [min-only] let the
// compiler squeeze to 64 regs (targeting 8/EU) -> 2.8GB of scratch spills.

typedef float f32x4 __attribute__((ext_vector_type(4)));
typedef __bf16 bf16x8 __attribute__((ext_vector_type(8)));

#define SWZ(row) (((row) & 7) << 4)

static __device__ __forceinline__ unsigned pkbf2(float a, float b) {
    unsigned short lo = __builtin_bit_cast(unsigned short, __float2bfloat16(a));
    unsigned short hi = __builtin_bit_cast(unsigned short, __float2bfloat16(b));
    return (unsigned)lo | ((unsigned)hi << 16);
}

// ---- pack W (512x512 row-major fp32) -> bf16 [c][n][32], c = k-chunk of 32 ----
__global__ void pack_w_kernel(const float* __restrict__ W,
                              __hip_bfloat16* __restrict__ out) {
    int i  = blockIdx.x * 512 + threadIdx.x;
    int c  = i >> 14;
    int n  = (i & 16383) >> 5;
    int kk = i & 31;
    out[i] = __float2bfloat16(W[n * 512 + (c << 5) + kk]);
}

// ---- pack W0 cols 0,1 -> contiguous [512][2] fp32 ----
__global__ void pack_w0_kernel(const float* __restrict__ W0,
                               float* __restrict__ w01) {
    int o = threadIdx.x;
    w01[o * 2 + 0] = W0[o * 34 + 0];
    w01[o * 2 + 1] = W0[o * 34 + 1];
}

// ---- c_step[k][o] = b0[o] + W0[o,2:34] . temb(t_k) ----
__global__ void cstep_kernel(const float* __restrict__ W0,
                             const float* __restrict__ b0,
                             float* __restrict__ cst) {
    int k = blockIdx.x;
    int o = threadIdx.x;
    float t = (float)k * 0.1f;
    float acc = b0[o];
    #pragma unroll
    for (int j = 0; j < 16; ++j) {
        float f   = expf(-9.210340371976184f * (float)j / 16.0f);
        float arg = t * f;
        acc += W0[o * 34 + 2 + j]  * sinf(arg);
        acc += W0[o * 34 + 18 + j] * cosf(arg);
    }
    cst[k * 512 + o] = acc;
}

__global__ __launch_bounds__(1024)
__attribute__((amdgpu_waves_per_eu(4, 4)))
void flow_kernel(const float* __restrict__ x,
                 const float* __restrict__ w01,
                 const float* __restrict__ cst,
                 const __hip_bfloat16* __restrict__ Wpk1,
                 const __hip_bfloat16* __restrict__ Wpk2,
                 const float* __restrict__ b1,
                 const float* __restrict__ b2,
                 const float* __restrict__ W3,
                 const float* __restrict__ b3v,
                 float* __restrict__ out)
{
    __shared__ __align__(16) __hip_bfloat16 Xbuf[96 * 512];  // 96 KB, XOR-swizzled rows
    __shared__ float zbuf[32][2];
    __shared__ float ldbuf[32];

    const int tid  = threadIdx.x;
    const int lane = tid & 63;
    const int wid  = tid >> 6;        // 0..15 -> n-slice n0w = wid*32
    const int l15  = lane & 15;
    const int lq   = lane >> 4;       // 0..3
    const int n0w  = wid << 5;
    const int wgs  = blockIdx.x << 5; // 32 samples per WG

    if (tid < 32) {
        zbuf[tid][0] = x[(wgs + tid) * 2 + 0];
        zbuf[tid][1] = x[(wgs + tid) * 2 + 1];
        ldbuf[tid]   = 0.0f;
    }

    // B-frag (X from LDS) addressing, strength-reduced:
    // off(mt,c) = row*1024 + (((c<<6)+lq16) ^ ((row&7)<<4)),  row = mt*16+l15
    //           = bbase[mt] + ((c<<6) ^ s6)
    // since row&7 = l15&7 (mt-independent), bits 4-5 fold into bbase, bit 6 -> s6.
    const int lq16 = lq << 4;
    const int s6   = (l15 & 4) << 4;
    int bbase[6];
    #pragma unroll
    for (int mt = 0; mt < 6; ++mt) {
        int row   = mt * 16 + l15;
        bbase[mt] = (row << 10) + (lq16 ^ ((l15 & 3) << 4));
    }
    const int abase = ((n0w + l15) << 2) + lq;   // uint4 index into packed W
    const uint4* Wp1 = (const uint4*)Wpk1;
    const uint4* Wp2 = (const uint4*)Wpk2;

    __syncthreads();

    #pragma unroll 1
    for (int step = 0; step < 10; ++step) {
        // ---------- layer 0 (rank-2 + step-constant): 16 outputs/thread ----------
        {
            const int s0 = tid >> 5;          // sample 0..31
            const int ob = (tid & 31) << 4;   // element base, 16 outs
            float z0 = zbuf[s0][0];
            float z1 = zbuf[s0][1];
            const float* cs = cst + (step << 9);
            const int swz = SWZ(s0);
            char* base0 = (char*)Xbuf + (s0 << 10);
            #pragma unroll
            for (int m = 0; m < 2; ++m) {
                unsigned ph[4], p0[4], p1[4];
                #pragma unroll
                for (int jj = 0; jj < 4; ++jj) {
                    float hv[2], u0v[2], u1v[2];
                    #pragma unroll
                    for (int k = 0; k < 2; ++k) {
                        int o = ob + m * 8 + jj * 2 + k;
                        float w00  = w01[o * 2 + 0];
                        float w01v = w01[o * 2 + 1];
                        float a   = fmaf(z0, w00, fmaf(z1, w01v, cs[o]));
                        float sig = 1.0f / (1.0f + __expf(-a));
                        float h   = a * sig;
                        float sp  = fmaf(h, 1.0f - sig, sig);   // silu'(a)
                        hv[k]  = h;
                        u0v[k] = sp * w00;
                        u1v[k] = sp * w01v;
                    }
                    ph[jj] = pkbf2(hv[0], hv[1]);
                    p0[jj] = pkbf2(u0v[0], u0v[1]);
                    p1[jj] = pkbf2(u1v[0], u1v[1]);
                }
                int off = ((ob + m * 8) * 2) ^ swz;
                uint4 vph = {ph[0], ph[1], ph[2], ph[3]};
                uint4 vp0 = {p0[0], p0[1], p0[2], p0[3]};
                uint4 vp1 = {p1[0], p1[1], p1[2], p1[3]};
                *(uint4*)(base0 + off)              = vph;
                *(uint4*)(base0 + (32 << 10) + off) = vp0;
                *(uint4*)(base0 + (64 << 10) + off) = vp1;
            }
        }
        __syncthreads();

        // ---------- layers 1, 2: D = W @ X^T, 512x96x512 ----------
        #pragma unroll 1
        for (int layer = 0; layer < 2; ++layer) {
            const uint4* __restrict__ Wp   = layer ? Wp2 : Wp1;
            const float* __restrict__ bias = layer ? b2  : b1;

            f32x4 acc[2][6];   // [n-tile][sample-tile]
            #pragma unroll
            for (int nt = 0; nt < 2; ++nt)
                #pragma unroll
                for (int mt = 0; mt < 6; ++mt)
                    acc[nt][mt] = (f32x4){0.f, 0.f, 0.f, 0.f};

            uint4  Af[2][2];   // W frags, depth-2 rotation
            bf16x8 Bf[6];      // X frags, single-buffered

            auto loada = [&](uint4 (&dst)[2], int c) {
                const uint4* p = Wp + c * 2048 + abase;
                dst[0] = p[0]; dst[1] = p[64];
            };

            loada(Af[0], 0);

            #pragma unroll
            for (int c = 0; c < 16; ++c) {
                if (c + 1 < 16) loada(Af[(c + 1) & 1], c + 1);
                const int cx = (c << 6) ^ s6;
                #pragma unroll
                for (int mt = 0; mt < 6; ++mt) {
                    Bf[mt] = __builtin_bit_cast(bf16x8,
                        *(const uint4*)((const char*)Xbuf + (bbase[mt] + cx)));
                }
                __builtin_amdgcn_s_setprio(1);
                #pragma unroll
                for (int mt = 0; mt < 6; ++mt)
                    #pragma unroll
                    for (int nt = 0; nt < 2; ++nt)
                        acc[nt][mt] = __builtin_amdgcn_mfma_f32_16x16x32_bf16(
                            __builtin_bit_cast(bf16x8, Af[c & 1][nt]),
                            Bf[mt], acc[nt][mt], 0, 0, 0);
                __builtin_amdgcn_s_setprio(0);
            }

            f32x4 bv[2];
            #pragma unroll
            for (int nt = 0; nt < 2; ++nt)
                bv[nt] = *(const f32x4*)(bias + n0w + nt * 16 + (lq << 2));

            __syncthreads();   // all waves done reading Xbuf before overwrite

            // epilogue: silu + JVP coupling; 12 uint2 LDS writes/thread
            #pragma unroll
            for (int mt = 0; mt < 2; ++mt) {
                int row = mt * 16 + l15;               // D col = sample
                char* pbase = (char*)Xbuf + (row << 10);
                int swz = SWZ(row);
                #pragma unroll
                for (int nt = 0; nt < 2; ++nt) {
                    unsigned hw[2], u0w[2], u1w[2];
                    #pragma unroll
                    for (int r2 = 0; r2 < 2; ++r2) {
                        float hv[2], u0v[2], u1v[2];
                        #pragma unroll
                        for (int k = 0; k < 2; ++k) {
                            int r = r2 * 2 + k;        // D row = n = n0w+nt*16+lq*4+r
                            float a   = acc[nt][mt][r] + bv[nt][r];
                            float sig = 1.0f / (1.0f + __expf(-a));
                            float h   = a * sig;
                            float sp  = fmaf(h, 1.0f - sig, sig);
                            hv[k]  = h;
                            u0v[k] = sp * acc[nt][mt + 2][r];
                            u1v[k] = sp * acc[nt][mt + 4][r];
                        }
                        hw[r2]  = pkbf2(hv[0], hv[1]);
                        u0w[r2] = pkbf2(u0v[0], u0v[1]);
                        u1w[r2] = pkbf2(u1v[0], u1v[1]);
                    }
                    int off = (((n0w + nt * 16 + (lq << 2)) * 2) ^ swz);
                    uint2 vh = {hw[0], hw[1]};
                    uint2 v0 = {u0w[0], u0w[1]};
                    uint2 v1 = {u1w[0], u1w[1]};
                    *(uint2*)(pbase + off)              = vh;
                    *(uint2*)(pbase + (32 << 10) + off) = v0;
                    *(uint2*)(pbase + (64 << 10) + off) = v1;
                }
            }
            __syncthreads();
        }

        // ---------- layer 3: six length-512 dots + state update ----------
        {
            const int s0   = tid >> 5;         // sample
            const int cidx = tid & 31;         // col-chunk: 16 elems
            float d0 = 0.f, d1 = 0.f, d2 = 0.f, d3 = 0.f, d4 = 0.f, d5 = 0.f;
            float wa[16], wb[16];
            const float4* w3r0 = (const float4*)W3 + (cidx << 2);
            const float4* w3r1 = (const float4*)W3 + 128 + (cidx << 2);
            #pragma unroll
            for (int q = 0; q < 4; ++q) {
                float4 v0 = w3r0[q], v1 = w3r1[q];
                wa[4*q+0]=v0.x; wa[4*q+1]=v0.y; wa[4*q+2]=v0.z; wa[4*q+3]=v0.w;
                wb[4*q+0]=v1.x; wb[4*q+1]=v1.y; wb[4*q+2]=v1.z; wb[4*q+3]=v1.w;
            }
            #pragma unroll
            for (int st = 0; st < 3; ++st) {
                int row = s0 + st * 32;
                const char* rb = (const char*)Xbuf + (row << 10);
                int swz = SWZ(row);
                float e[16];
                #pragma unroll
                for (int q = 0; q < 2; ++q) {
                    int off = (((cidx << 5) + (q << 4)) ^ swz);
                    uint4 v = *(const uint4*)(rb + off);
                    unsigned uu[4] = {v.x, v.y, v.z, v.w};
                    #pragma unroll
                    for (int w = 0; w < 4; ++w) {
                        e[q*8 + 2*w]   = __uint_as_float(uu[w] << 16);
                        e[q*8 + 2*w+1] = __uint_as_float(uu[w] & 0xffff0000u);
                    }
                }
                float sa = 0.f, sb = 0.f;
                #pragma unroll
                for (int j = 0; j < 16; ++j) {
                    sa = fmaf(wa[j], e[j], sa);
                    sb = fmaf(wb[j], e[j], sb);
                }
                if      (st == 0) { d0 = sa; d1 = sb; }
                else if (st == 1) { d2 = sa; d3 = sb; }
                else              { d4 = sa; d5 = sb; }
            }
            #pragma unroll
            for (int m = 1; m < 32; m <<= 1) {
                d0 += __shfl_xor(d0, m);
                d1 += __shfl_xor(d1, m);
                d2 += __shfl_xor(d2, m);
                d3 += __shfl_xor(d3, m);
                d4 += __shfl_xor(d4, m);
                d5 += __shfl_xor(d5, m);
            }
            if ((tid & 31) == 0) {
                float v0 = d0 + b3v[0];
                float v1 = d1 + b3v[1];
                float det = (1.0f + 0.1f * d2) * (1.0f + 0.1f * d5)
                          - 0.01f * d4 * d3;
                ldbuf[s0] += logf(fmaxf(fabsf(det), 1e-8f));
                zbuf[s0][0] += 0.1f * v0;
                zbuf[s0][1] += 0.1f * v1;
            }
        }
        __syncthreads();
    }

    if (tid < 32) {
        float z0 = zbuf[tid][0], z1 = zbuf[tid][1];
        out[wgs + tid] = -0.5f * (z0 * z0 + z1 * z1) - 1.8378770664093453f + ldbuf[tid];
    }
}

extern "C" void kernel_launch(void* const* d_in, const int* in_sizes, int n_in,
                              void* d_out, int out_size, void* d_ws, size_t ws_size,
                              hipStream_t stream) {
    const float* x  = (const float*)d_in[0];
    const float* W0 = (const float*)d_in[1];   // (512, 34)
    const float* b0 = (const float*)d_in[2];
    const float* W1 = (const float*)d_in[3];   // (512, 512)
    const float* b1 = (const float*)d_in[4];
    const float* W2 = (const float*)d_in[5];
    const float* b2 = (const float*)d_in[6];
    const float* W3 = (const float*)d_in[7];   // (2, 512)
    const float* b3 = (const float*)d_in[8];
    float* out = (float*)d_out;

    char* ws = (char*)d_ws;
    __hip_bfloat16* wpk1 = (__hip_bfloat16*)ws;                  // 512 KB
    __hip_bfloat16* wpk2 = (__hip_bfloat16*)(ws + (512u << 10)); // 512 KB
    float*          cstp = (float*)(ws + (1024u << 10));         // 20 KB
    float*          w01p = (float*)(ws + (1044u << 10));         // 4 KB

    pack_w_kernel<<<512, 512, 0, stream>>>(W1, wpk1);
    pack_w_kernel<<<512, 512, 0, stream>>>(W2, wpk2);
    cstep_kernel<<<10, 512, 0, stream>>>(W0, b0, cstp);
    pack_w0_kernel<<<1, 512, 0, stream>>>(W0, w01p);
    flow_kernel<<<131072 / 32, 1024, 0, stream>>>(x, w01p, cstp, wpk1, wpk2,
                                                  b1, b2, W3, b3, out);
}